// Round 3
// baseline (296.704 us; speedup 1.0000x reference)
//
#include <hip/hip_runtime.h>

// Problem constants
#define BATCH 1024
#define SEQ   336
#define CCH   64      // channels
#define ORD   168     // order (K)
#define TT    96      // tar_seq
#define OFF   168     // SEQ - ORD

// Tile config: lane = batch; wave = (channel, 24-wide t-window)
#define KO     28            // K per chunk; 6*28 = 168
#define NCHUNK 6
#define CPB    4             // channels per block
#define BPB    64            // batches per block (= wavefront)
#define THB    48            // t per block (half of TT)
#define TW     24            // t per wave
#define XCHUNK (KO*CPB*BPB)  // 7168 floats per buffer

typedef float v8f __attribute__((ext_vector_type(8)));

__global__ __launch_bounds__(512, 4)
void tcl_kernel(const float* __restrict__ inp,   // [B][SEQ][C]
                const float* __restrict__ W,     // [C][ORD][T]
                const float* __restrict__ bias,  // [C][T]
                float* __restrict__ out)         // [B][T][C]
{
    // X double buffer: [2][KO][CPB][BPB] = 57344 B. Epilogue reuses it as
    // Ys[24][64][5] (7680 floats).
    __shared__ float smem[2 * XCHUNK];

    const int tid  = threadIdx.x;
    const int lane = tid & 63;                               // = batch within tile
    const int wid  = __builtin_amdgcn_readfirstlane(tid >> 6); // 0..7, forced uniform
    const int cl   = wid & 3;                                // wave's channel (local)
    const int tw   = wid >> 2;                               // wave's t-window (0/1)

    // grid = btile(16) + cblk(16)*16 + thalf(2)*256; same btile -> same XCD
    const int btile = blockIdx.x & 15;
    const int cblk  = (blockIdx.x >> 4) & 15;
    const int th    = blockIdx.x >> 8;
    const int b0 = btile * BPB;
    const int c0 = cblk * CPB;
    const int t0 = th * THB + tw * TW;    // wave's global t start

    // Wave-uniform W row base (uniform because wid is readfirstlane'd)
    const float* Wc = W + (size_t)(c0 + cl) * ORD * TT + t0;
    const v8f bv0 = *(const v8f*)(bias + (c0 + cl) * TT + t0);
    const v8f bv1 = *(const v8f*)(bias + (c0 + cl) * TT + t0 + 8);
    const v8f bv2 = *(const v8f*)(bias + (c0 + cl) * TT + t0 + 16);

    float acc[TW];
    #pragma unroll
    for (int j = 0; j < TW; ++j) acc[j] = 0.f;

    // ---- stage chunk 0: inputs[b0+b][OFF + o][c0..c0+3] -> Xs0[o][c][b]
    float4 xr[4];
    #pragma unroll
    for (int r = 0; r < 4; ++r) {
        int v = tid + r * 512;
        if (v < KO * BPB) {
            int o = v >> 6, b = v & 63;
            xr[r] = *(const float4*)(inp +
                ((size_t)(b0 + b) * SEQ + OFF + o) * CCH + c0);
        }
    }
    #pragma unroll
    for (int r = 0; r < 4; ++r) {
        int v = tid + r * 512;
        if (v < KO * BPB) {
            int o = v >> 6, b = v & 63;
            float* d = smem + o * (CPB * BPB) + b;  // buffer 0
            d[0] = xr[r].x; d[64] = xr[r].y; d[128] = xr[r].z; d[192] = xr[r].w;
        }
    }
    __syncthreads();

    for (int k = 0; k < NCHUNK; ++k) {
        // issue next chunk's gathers early; they drain under the FMA burst
        if (k + 1 < NCHUNK) {
            #pragma unroll
            for (int r = 0; r < 4; ++r) {
                int v = tid + r * 512;
                if (v < KO * BPB) {
                    int o = v >> 6, b = v & 63;
                    xr[r] = *(const float4*)(inp +
                        ((size_t)(b0 + b) * SEQ + OFF + (k + 1) * KO + o) * CCH + c0);
                }
            }
        }

        // ---- compute chunk k: 1 conflict-free ds_read_b32 + 24 SGPR-FMAs per o
        const float* Xb = smem + (k & 1) * XCHUNK + cl * BPB + lane;
        const float* Wk = Wc + (size_t)(k * KO) * TT;
        for (int o = 0; o < KO; ++o) {
            float x = Xb[o * (CPB * BPB)];
            v8f w0 = *(const v8f*)(Wk + o * TT);
            v8f w1 = *(const v8f*)(Wk + o * TT + 8);
            v8f w2 = *(const v8f*)(Wk + o * TT + 16);
            #pragma unroll
            for (int j = 0; j < 8; ++j) acc[j]      = fmaf(x, w0[j], acc[j]);
            #pragma unroll
            for (int j = 0; j < 8; ++j) acc[8 + j]  = fmaf(x, w1[j], acc[8 + j]);
            #pragma unroll
            for (int j = 0; j < 8; ++j) acc[16 + j] = fmaf(x, w2[j], acc[16 + j]);
        }

        // ---- commit staged chunk into the other buffer
        if (k + 1 < NCHUNK) {
            float* dbase = smem + ((k + 1) & 1) * XCHUNK;
            #pragma unroll
            for (int r = 0; r < 4; ++r) {
                int v = tid + r * 512;
                if (v < KO * BPB) {
                    int o = v >> 6, b = v & 63;
                    float* d = dbase + o * (CPB * BPB) + b;
                    d[0] = xr[r].x; d[64] = xr[r].y; d[128] = xr[r].z; d[192] = xr[r].w;
                }
            }
        }
        __syncthreads();
    }

    // ---- epilogue: bias + c-transpose through LDS -> float4 stores on c.
    // Ys[tl][b][cl] with pad-5 stride: all LDS accesses conflict-free.
    float* Ys = smem;
    #pragma unroll
    for (int rnd = 0; rnd < 2; ++rnd) {
        if (tw == rnd) {
            #pragma unroll
            for (int j = 0; j < TW; ++j) {
                float bj = (j < 8) ? bv0[j] : (j < 16) ? bv1[j - 8] : bv2[j - 16];
                Ys[(j * 64 + lane) * 5 + cl] = acc[j] + bj;
            }
        }
        __syncthreads();
        {
            int b  = tid & 63;
            int wv = tid >> 6;
            #pragma unroll
            for (int s = 0; s < 3; ++s) {
                int tl = wv + s * 8;     // 0..23
                const float* p = Ys + (tl * 64 + b) * 5;
                float4 y4 = make_float4(p[0], p[1], p[2], p[3]);
                *(float4*)(out +
                    ((size_t)(b0 + b) * TT + th * THB + rnd * TW + tl) * CCH + c0) = y4;
            }
        }
        __syncthreads();   // Ys reused next round
    }
}

extern "C" void kernel_launch(void* const* d_in, const int* in_sizes, int n_in,
                              void* d_out, int out_size, void* d_ws, size_t ws_size,
                              hipStream_t stream) {
    const float* inp  = (const float*)d_in[0];   // [1024][336][64]
    const float* W    = (const float*)d_in[1];   // [64][168][96]
    const float* bias = (const float*)d_in[2];   // [64][96]
    float* out = (float*)d_out;                  // [1024][96][64]

    dim3 grid(512);          // 16 btile x 16 cblk x 2 t-half; 2 blocks/CU
    dim3 block(512);         // 8 waves = 4 channels x 2 t-windows
    tcl_kernel<<<grid, block, 0, stream>>>(inp, W, bias, out);
}

// Round 4
// 182.217 us; speedup vs baseline: 1.6283x; 1.6283x over previous
//
#include <hip/hip_runtime.h>
#include <hip/hip_bf16.h>

// Problem constants
#define BATCH 1024
#define SEQ   336
#define CCH   64
#define ORD   168
#define TT    96
#define OFF   168
#define KP    192            // K padded to 6 chunks of 32

typedef __attribute__((ext_vector_type(8))) short  short8;   // 8 bf16 (MFMA frag)
typedef __attribute__((ext_vector_type(8))) unsigned short ushort8;
typedef __attribute__((ext_vector_type(4))) float  floatx4;

#define XB_ELEMS ((size_t)CCH * BATCH * KP)               // 12,582,912
#define WT_ELEMS ((size_t)CCH * TT * KP)                  //  1,179,648
#define WS_NEED  ((XB_ELEMS + WT_ELEMS) * 2)              // 27,525,120 B

__device__ __forceinline__ unsigned short f2bf(float f) {
    union { float f; unsigned u; } v; v.f = f;
    unsigned r = v.u + 0x7FFF + ((v.u >> 16) & 1);        // RNE
    return (unsigned short)(r >> 16);
}

// ============ K1: transpose + fp32->bf16 convert into workspace ============
// X part (blocks 0..1535): inp[b][168+o][c] -> Xb[c][b][k], k>=168 zeroed.
// W part (blocks 1536..1727): W[c][o][t]    -> Wt[c][t][k], k>=168 zeroed.
__global__ __launch_bounds__(256)
void k1_transpose(const float* __restrict__ inp, const float* __restrict__ W,
                  unsigned short* __restrict__ Xb, unsigned short* __restrict__ Wt)
{
    const int tid = threadIdx.x;
    const int l   = tid & 63;
    const int w   = tid >> 6;
    const int o4  = l >> 4;          // 0..3
    const int q   = l & 15;

    if (blockIdx.x < 1536) {
        // ---- X: wave = (b, o-block of 32). 6144 waves.
        const int wid  = blockIdx.x * 4 + w;
        const int b    = wid & 1023;
        const int oblk = wid >> 10;              // 0..5
        const int ob   = oblk * 32 + o4 * 8;     // this thread's 8 consecutive k
        floatx4 f[8];
        #pragma unroll
        for (int i = 0; i < 8; ++i) {
            int o = ob + i;
            floatx4 z = 0.f;
            f[i] = (o < ORD)
                ? *(const floatx4*)(inp + ((size_t)b * SEQ + OFF + o) * CCH + q * 4)
                : z;
        }
        #pragma unroll
        for (int j = 0; j < 4; ++j) {
            int c = q * 4 + j;
            ushort8 u;
            #pragma unroll
            for (int i = 0; i < 8; ++i) u[i] = f2bf(f[i][j]);
            *(ushort8*)(Xb + ((size_t)c * BATCH + b) * KP + ob) = u;
        }
    } else {
        // ---- W: wave = (c, o-block, t-half of 48). 768 waves; lanes q<12 active.
        const int wid  = (blockIdx.x - 1536) * 4 + w;
        const int c    = wid & 63;
        const int rest = wid >> 6;               // 0..11
        const int oblk = rest % 6;
        const int th   = rest / 6;               // 0..1
        const int ob   = oblk * 32 + o4 * 8;
        const bool act = (q < 12);
        floatx4 f[8];
        #pragma unroll
        for (int i = 0; i < 8; ++i) {
            int o = ob + i;
            floatx4 z = 0.f;
            f[i] = (act && o < ORD)
                ? *(const floatx4*)(W + ((size_t)c * ORD + o) * TT + th * 48 + q * 4)
                : z;
        }
        if (act) {
            #pragma unroll
            for (int j = 0; j < 4; ++j) {
                int t = th * 48 + q * 4 + j;
                ushort8 u;
                #pragma unroll
                for (int i = 0; i < 8; ++i) u[i] = f2bf(f[i][j]);
                *(ushort8*)(Wt + ((size_t)c * TT + t) * KP + ob) = u;
            }
        }
    }
}

// ============ K2: per-channel bf16 MFMA GEMM, fragments from global ============
// Block = (c, btile of 64). Wave = 16 b x 96 t. No LDS.
// Swizzle: XCD = blockIdx%8 = btile&7 -> all 64 c-blocks of a btile share an XCD
// so the 16-channel output lines merge in that XCD's L2.
__global__ __launch_bounds__(256)
void k2_gemm(const unsigned short* __restrict__ Xb,
             const unsigned short* __restrict__ Wt,
             const float* __restrict__ bias, float* __restrict__ out)
{
    const int tid = threadIdx.x;
    const int l   = tid & 63;
    const int wv  = tid >> 6;
    const int m   = l & 15;          // MFMA row (A) / col (D)
    const int kg  = l >> 4;          // k-group (quad)

    const int btl = (blockIdx.x & 7) | ((blockIdx.x >> 9) << 3);  // 0..15
    const int c   = (blockIdx.x >> 3) & 63;
    const int b0  = btl * 64 + wv * 16;

    // A: this lane's 6 fragments = its full 192-k row quarter (6 x 16 B, stride 64 B)
    const unsigned short* Arow = Xb + ((size_t)c * BATCH + b0 + m) * KP + kg * 8;
    short8 a[6];
    #pragma unroll
    for (int k = 0; k < 6; ++k) a[k] = *(const short8*)(Arow + k * 32);

    const unsigned short* Brow = Wt + ((size_t)c * TT + m) * KP + kg * 8;

    floatx4 acc[6] = {};
    #pragma unroll
    for (int k = 0; k < 6; ++k) {
        #pragma unroll
        for (int n = 0; n < 6; ++n) {
            short8 bf = *(const short8*)(Brow + (size_t)(n * 16) * KP + k * 32);
            acc[n] = __builtin_amdgcn_mfma_f32_16x16x32_bf16(a[k], bf, acc[n], 0, 0, 0);
        }
    }

    // Epilogue: D[row=b][col=t]; scalar stores, L2 merges 16 c per line (swizzle).
    #pragma unroll
    for (int n = 0; n < 6; ++n) {
        float bn = bias[c * TT + n * 16 + m];
        #pragma unroll
        for (int r = 0; r < 4; ++r) {
            int row = b0 + kg * 4 + r;
            out[((size_t)row * TT + n * 16 + m) * CCH + c] = acc[n][r] + bn;
        }
    }
}

// ============ Fallback (round-2 kernel, used only if ws too small) ============
#define MB  8
#define NT  16
#define KO  8
#define NCH (ORD/KO)
#define WSTRIDE 132
typedef __attribute__((address_space(3))) void* lds_ptr_t;
typedef const __attribute__((address_space(1))) void* gbl_ptr_t;

__global__ __launch_bounds__(256, 4)
void tcl_fallback(const float* __restrict__ inp, const float* __restrict__ W,
                  const float* __restrict__ bias, float* __restrict__ out)
{
    __shared__ float Xs[MB * KO * CCH];
    __shared__ float Ws[CCH * WSTRIDE];
    const int tid = threadIdx.x;
    const int c   = tid & 63;
    const int tg  = tid >> 6;
    const int bblk = blockIdx.x & 127;
    const int tblk = blockIdx.x >> 7;
    const int b0 = bblk * MB;
    const int t0 = tblk * NT;
    float acc[MB][4];
    #pragma unroll
    for (int bi = 0; bi < MB; ++bi)
        #pragma unroll
        for (int tj = 0; tj < 4; ++tj) acc[bi][tj] = 0.f;
    for (int ch = 0; ch < NCH; ++ch) {
        const int ob = ch * KO;
        #pragma unroll
        for (int k = 0; k < 4; ++k) {
            int v = tid + k * 256;
            int row = v >> 4, c4 = v & 15;
            int bi = row >> 3, oi = row & 7;
            const float* gp = inp + ((size_t)(b0 + bi) * SEQ + (OFF + ob + oi)) * CCH + c4 * 4;
            __builtin_amdgcn_global_load_lds((gbl_ptr_t)gp, (lds_ptr_t)(Xs + v * 4), 16, 0, 0);
        }
        float4 wbuf[8];
        #pragma unroll
        for (int k = 0; k < 8; ++k) {
            int v = tid + k * 256;
            int cc = v >> 5, oi = (v >> 2) & 7, t4 = v & 3;
            wbuf[k] = *(const float4*)(W + (size_t)cc * (ORD * TT) + (size_t)(ob + oi) * TT + t0 + t4 * 4);
        }
        #pragma unroll
        for (int k = 0; k < 8; ++k) {
            int v = tid + k * 256;
            int cc = v >> 5, oi = (v >> 2) & 7, t4 = v & 3;
            *(float4*)(Ws + cc * WSTRIDE + oi * NT + t4 * 4) = wbuf[k];
        }
        __syncthreads();
        #pragma unroll
        for (int oi = 0; oi < KO; ++oi) {
            const float4 wv = *(const float4*)(Ws + c * WSTRIDE + oi * NT + tg * 4);
            float xv[MB];
            #pragma unroll
            for (int bi = 0; bi < MB; ++bi) xv[bi] = Xs[(bi * KO + oi) * CCH + c];
            #pragma unroll
            for (int bi = 0; bi < MB; ++bi) {
                acc[bi][0] += xv[bi] * wv.x;
                acc[bi][1] += xv[bi] * wv.y;
                acc[bi][2] += xv[bi] * wv.z;
                acc[bi][3] += xv[bi] * wv.w;
            }
        }
        __syncthreads();
    }
    const float4 bv = *(const float4*)(bias + c * TT + t0 + tg * 4);
    #pragma unroll
    for (int bi = 0; bi < MB; ++bi) {
        size_t base = ((size_t)(b0 + bi) * TT + (t0 + tg * 4)) * CCH + c;
        out[base]           = acc[bi][0] + bv.x;
        out[base + CCH]     = acc[bi][1] + bv.y;
        out[base + 2 * CCH] = acc[bi][2] + bv.z;
        out[base + 3 * CCH] = acc[bi][3] + bv.w;
    }
}

extern "C" void kernel_launch(void* const* d_in, const int* in_sizes, int n_in,
                              void* d_out, int out_size, void* d_ws, size_t ws_size,
                              hipStream_t stream) {
    const float* inp  = (const float*)d_in[0];   // [1024][336][64]
    const float* W    = (const float*)d_in[1];   // [64][168][96]
    const float* bias = (const float*)d_in[2];   // [64][96]
    float* out = (float*)d_out;                  // [1024][96][64]

    if (ws_size >= WS_NEED) {
        unsigned short* Xb = (unsigned short*)d_ws;
        unsigned short* Wt = Xb + XB_ELEMS;
        k1_transpose<<<1728, 256, 0, stream>>>(inp, W, Xb, Wt);
        k2_gemm<<<1024, 256, 0, stream>>>(Xb, Wt, bias, out);
    } else {
        tcl_fallback<<<768, 256, 0, stream>>>(inp, W, bias, out);
    }
}

// Round 5
// 146.818 us; speedup vs baseline: 2.0209x; 1.2411x over previous
//
#include <hip/hip_runtime.h>

// Problem constants
#define BATCH 1024
#define SEQ   336
#define CCH   64
#define ORD   168
#define TT    96
#define OFF   168
#define KP    192            // K padded to 6 chunks of 32
#define NKC   6              // 32-k MFMA chunks
#define NCHK  24             // 16-B (8-k) chunks per row
#define RSC   25             // row stride in 16-B chunks (+1 pad)

typedef __attribute__((ext_vector_type(8))) short  short8;    // MFMA bf16 frag
typedef __attribute__((ext_vector_type(8))) unsigned short ushort8;
typedef __attribute__((ext_vector_type(4))) float  floatx4;

#define WT2_ELEMS ((size_t)CCH * 36 * 512)   // 64c x (6n*6kc) x 64lane*8 = 1,179,648 ushorts
#define WS_NEED   (WT2_ELEMS * 2)            // 2.25 MB

__device__ __forceinline__ unsigned short f2bf(float f) {
    union { float f; unsigned u; } v; v.f = f;
    unsigned r = v.u + 0x7FFF + ((v.u >> 16) & 1);   // RNE
    return (unsigned short)(r >> 16);
}

// ===== k1w: pack W[c][o][t] into MFMA B-fragment order =====
// Wt2[((c*6+n)*6+kc)*512 + lane*8 + j] = bf16(W[c][kc*32 + (lane>>4)*8 + j][n*16 + (lane&15)])
// (zero-padded for o >= 168). Consumer loads are wave-uniform + lane*16B.
__global__ __launch_bounds__(256)
void k1w(const float* __restrict__ W, unsigned short* __restrict__ Wt2)
{
    const int tid = threadIdx.x, l = tid & 63, w = tid >> 6;
    const int wid = blockIdx.x * 4 + w;          // 0..2303 = (c,n,kc)
    const int kc = wid % 6;
    const int n  = (wid / 6) % 6;
    const int c  = wid / 36;
    const int m  = l & 15, kg = l >> 4;
    const int t  = n * 16 + m;
    ushort8 u;
    #pragma unroll
    for (int j = 0; j < 8; ++j) {
        int o = kc * 32 + kg * 8 + j;
        float val = (o < ORD) ? W[((size_t)c * ORD + o) * TT + t] : 0.f;
        u[j] = f2bf(val);
    }
    *(ushort8*)(Wt2 + (size_t)wid * 512 + l * 8) = u;
}

// ===== k2f: fused transpose + per-channel bf16 MFMA GEMM =====
// Block = 8 c x 16 b x 96 t, 256 threads (4 waves, 2 c each). 512 blocks = 2/CU.
// XCD swizzle: blockIdx%8 == btile%8 -> the 8 c-group blocks of a btile share
// an XCD: X lines fetched once, output lines merged in that L2.
__global__ __launch_bounds__(256, 2)
void k2f(const float* __restrict__ inp, const unsigned short* __restrict__ Wt2,
         const float* __restrict__ bias, float* __restrict__ out)
{
    __shared__ unsigned short Xs[8 * 16 * RSC * 8];   // 51200 B; reused as Ys in epilogue

    const int tid = threadIdx.x, l = tid & 63, wv = tid >> 6;
    const int m = l & 15, kg = l >> 4;
    const int btile = (blockIdx.x & 7) | ((blockIdx.x >> 6) << 3);   // 0..63
    const int cg    = (blockIdx.x >> 3) & 7;                          // 0..7
    const int b0 = btile * 16, c0 = cg * 8;

    // ---- stage X: inp[b0+b][OFF+k][c0..c0+7] -> Xs[c][b][chunk^(c&7)] bf16
    // 768 lane-tasks: (cq 2, b 16, kchunk 24); lanes = (cq,b) -> 32-B runs.
    #pragma unroll
    for (int i = 0; i < 3; ++i) {
        int v = tid + i * 256;
        int cq = v & 1, b = (v >> 1) & 15, kchunk = v >> 5;   // 0..23
        floatx4 f[8];
        #pragma unroll
        for (int j = 0; j < 8; ++j) {
            int o = kchunk * 8 + j;
            floatx4 z = {0.f, 0.f, 0.f, 0.f};
            f[j] = (o < ORD)
                ? *(const floatx4*)(inp + ((size_t)(b0 + b) * SEQ + OFF + o) * CCH + c0 + cq * 4)
                : z;
        }
        #pragma unroll
        for (int cc = 0; cc < 4; ++cc) {
            int c = cq * 4 + cc;                 // local channel 0..7
            ushort8 u;
            #pragma unroll
            for (int j = 0; j < 8; ++j) u[j] = f2bf(f[j][cc]);
            *(ushort8*)(Xs + (((c * 16 + b) * RSC + (kchunk ^ (c & 7))) << 3)) = u;
        }
    }

    // bias for this wave's 2 channels (lane's t = n*16+m)
    float bv[2][6];
    #pragma unroll
    for (int cc = 0; cc < 2; ++cc)
        #pragma unroll
        for (int n = 0; n < 6; ++n)
            bv[cc][n] = bias[(c0 + wv * 2 + cc) * TT + n * 16 + m];

    __syncthreads();

    // ---- compute: per wave, 2 channels x (16b x 96t x 192k)
    floatx4 acc[2][6] = {};
    #pragma unroll
    for (int cc = 0; cc < 2; ++cc) {
        const int c = wv * 2 + cc;               // local channel
        short8 a[6];
        #pragma unroll
        for (int kc = 0; kc < 6; ++kc) {
            int chunk = (kc * 4 + kg) ^ (c & 7);
            a[kc] = *(const short8*)(Xs + (((c * 16 + m) * RSC + chunk) << 3));
        }
        const unsigned short* Wc = Wt2 + (size_t)(c0 + c) * 36 * 512;
        #pragma unroll
        for (int kc = 0; kc < 6; ++kc) {
            #pragma unroll
            for (int n = 0; n < 6; ++n) {
                short8 bfrag = *(const short8*)(Wc + (size_t)(n * 6 + kc) * 512 + l * 8);
                acc[cc][n] = __builtin_amdgcn_mfma_f32_16x16x32_bf16(a[kc], bfrag, acc[cc][n], 0, 0, 0);
            }
        }
    }

    __syncthreads();   // done reading Xs; reuse as Ys

    // ---- epilogue: per n-slice, LDS transpose -> 32-B contiguous c-runs
    // Ys[row][t][c]: addr = row*196 + t*12 + c (float4-aligned, <=4-way wr conflicts)
    float* Ys = (float*)Xs;
    #pragma unroll
    for (int n = 0; n < 6; ++n) {
        #pragma unroll
        for (int cc = 0; cc < 2; ++cc) {
            int c = wv * 2 + cc;
            #pragma unroll
            for (int r = 0; r < 4; ++r) {
                int row = kg * 4 + r;            // D row = local b
                Ys[row * 196 + m * 12 + c] = acc[cc][n][r] + bv[cc][n];
            }
        }
        __syncthreads();
        {
            int c4 = tid & 1, t = (tid >> 1) & 15, r8 = tid >> 5;   // r8 0..7
            #pragma unroll
            for (int rep = 0; rep < 2; ++rep) {
                int row = rep * 8 + r8;
                floatx4 y = *(const floatx4*)(Ys + row * 196 + t * 12 + c4 * 4);
                *(floatx4*)(out + ((size_t)(b0 + row) * TT + n * 16 + t) * CCH + c0 + c4 * 4) = y;
            }
        }
        __syncthreads();
    }
}

// ===== fallback (round-2 kernel) if ws too small =====
#define MB  8
#define NT  16
#define KO  8
#define NCH (ORD/KO)
#define WSTRIDE 132
typedef __attribute__((address_space(3))) void* lds_ptr_t;
typedef const __attribute__((address_space(1))) void* gbl_ptr_t;

__global__ __launch_bounds__(256, 4)
void tcl_fallback(const float* __restrict__ inp, const float* __restrict__ W,
                  const float* __restrict__ bias, float* __restrict__ out)
{
    __shared__ float Xsf[MB * KO * CCH];
    __shared__ float Wsf[CCH * WSTRIDE];
    const int tid = threadIdx.x;
    const int c   = tid & 63;
    const int tg  = tid >> 6;
    const int bblk = blockIdx.x & 127;
    const int tblk = blockIdx.x >> 7;
    const int b0 = bblk * MB;
    const int t0 = tblk * NT;
    float acc[MB][4];
    #pragma unroll
    for (int bi = 0; bi < MB; ++bi)
        #pragma unroll
        for (int tj = 0; tj < 4; ++tj) acc[bi][tj] = 0.f;
    for (int ch = 0; ch < NCH; ++ch) {
        const int ob = ch * KO;
        #pragma unroll
        for (int k = 0; k < 4; ++k) {
            int v = tid + k * 256;
            int row = v >> 4, c4 = v & 15;
            int bi = row >> 3, oi = row & 7;
            const float* gp = inp + ((size_t)(b0 + bi) * SEQ + (OFF + ob + oi)) * CCH + c4 * 4;
            __builtin_amdgcn_global_load_lds((gbl_ptr_t)gp, (lds_ptr_t)(Xsf + v * 4), 16, 0, 0);
        }
        float4 wbuf[8];
        #pragma unroll
        for (int k = 0; k < 8; ++k) {
            int v = tid + k * 256;
            int cch = v >> 5, oi = (v >> 2) & 7, t4 = v & 3;
            wbuf[k] = *(const float4*)(W + (size_t)cch * (ORD * TT) + (size_t)(ob + oi) * TT + t0 + t4 * 4);
        }
        #pragma unroll
        for (int k = 0; k < 8; ++k) {
            int v = tid + k * 256;
            int cch = v >> 5, oi = (v >> 2) & 7, t4 = v & 3;
            *(float4*)(Wsf + cch * WSTRIDE + oi * NT + t4 * 4) = wbuf[k];
        }
        __syncthreads();
        #pragma unroll
        for (int oi = 0; oi < KO; ++oi) {
            const float4 wvv = *(const float4*)(Wsf + c * WSTRIDE + oi * NT + tg * 4);
            float xv[MB];
            #pragma unroll
            for (int bi = 0; bi < MB; ++bi) xv[bi] = Xsf[(bi * KO + oi) * CCH + c];
            #pragma unroll
            for (int bi = 0; bi < MB; ++bi) {
                acc[bi][0] += xv[bi] * wvv.x;
                acc[bi][1] += xv[bi] * wvv.y;
                acc[bi][2] += xv[bi] * wvv.z;
                acc[bi][3] += xv[bi] * wvv.w;
            }
        }
        __syncthreads();
    }
    const float4 bvv = *(const float4*)(bias + c * TT + t0 + tg * 4);
    #pragma unroll
    for (int bi = 0; bi < MB; ++bi) {
        size_t base = ((size_t)(b0 + bi) * TT + (t0 + tg * 4)) * CCH + c;
        out[base]           = acc[bi][0] + bvv.x;
        out[base + CCH]     = acc[bi][1] + bvv.y;
        out[base + 2 * CCH] = acc[bi][2] + bvv.z;
        out[base + 3 * CCH] = acc[bi][3] + bvv.w;
    }
}

extern "C" void kernel_launch(void* const* d_in, const int* in_sizes, int n_in,
                              void* d_out, int out_size, void* d_ws, size_t ws_size,
                              hipStream_t stream) {
    const float* inp  = (const float*)d_in[0];   // [1024][336][64]
    const float* W    = (const float*)d_in[1];   // [64][168][96]
    const float* bias = (const float*)d_in[2];   // [64][96]
    float* out = (float*)d_out;                  // [1024][96][64]

    if (ws_size >= WS_NEED) {
        unsigned short* Wt2 = (unsigned short*)d_ws;
        k1w<<<576, 256, 0, stream>>>(W, Wt2);
        k2f<<<512, 256, 0, stream>>>(inp, Wt2, bias, out);
    } else {
        tcl_fallback<<<768, 256, 0, stream>>>(inp, W, bias, out);
    }
}

// Round 6
// 146.746 us; speedup vs baseline: 2.0219x; 1.0005x over previous
//
#include <hip/hip_runtime.h>

// Problem constants
#define BATCH 1024
#define SEQ   336
#define CCH   64
#define ORD   168
#define TT    96
#define OFF   168
#define KP    192            // K padded to 6 chunks of 32
#define RSC   25             // Xs row stride in 16-B chunks (+1 pad)
#define YSTR  9              // Ys per-t stride in floats (8 c + 1 pad)

typedef __attribute__((ext_vector_type(8))) short  short8;    // MFMA bf16 frag
typedef __attribute__((ext_vector_type(8))) unsigned short ushort8;
typedef __attribute__((ext_vector_type(4))) float  floatx4;

#define WT2_ELEMS ((size_t)CCH * 36 * 512)   // packed W frags: 1,179,648 ushorts
#define WS_NEED   (WT2_ELEMS * 2)            // 2.25 MB

__device__ __forceinline__ unsigned short f2bf(float f) {
    union { float f; unsigned u; } v; v.f = f;
    unsigned r = v.u + 0x7FFF + ((v.u >> 16) & 1);   // RNE
    return (unsigned short)(r >> 16);
}

// ===== k1w: pack W[c][o][t] into MFMA B-fragment order (unchanged, proven) =====
__global__ __launch_bounds__(256)
void k1w(const float* __restrict__ W, unsigned short* __restrict__ Wt2)
{
    const int tid = threadIdx.x, l = tid & 63, w = tid >> 6;
    const int wid = blockIdx.x * 4 + w;          // 0..2303 = (c,n,kc)
    const int kc = wid % 6;
    const int n  = (wid / 6) % 6;
    const int c  = wid / 36;
    const int m  = l & 15, kg = l >> 4;
    const int t  = n * 16 + m;
    ushort8 u;
    #pragma unroll
    for (int j = 0; j < 8; ++j) {
        int o = kc * 32 + kg * 8 + j;
        float val = (o < ORD) ? W[((size_t)c * ORD + o) * TT + t] : 0.f;
        u[j] = f2bf(val);
    }
    *(ushort8*)(Wt2 + (size_t)wid * 512 + l * 8) = u;
}

// ===== k2f: fused transpose + per-channel bf16 MFMA GEMM =====
// Block = 8 c x 16 b x 96 t, 512 threads = 8 waves, 1 channel per wave.
// 512 blocks -> 2 blocks/CU (LDS 55.3 KB) -> 16 waves/CU = 4 waves/SIMD.
// XCD swizzle: blockIdx%8 == btile%8 -> 8 c-group blocks of a btile share an
// XCD: X lines fetched once into L2, output lines merged in L2.
__global__ __launch_bounds__(512, 4)
void k2f(const float* __restrict__ inp, const unsigned short* __restrict__ Wt2,
         const float* __restrict__ bias, float* __restrict__ out)
{
    __shared__ float smem_f[16 * TT * YSTR];          // 55296 B (Ys); Xs aliases it
    unsigned short* Xs = (unsigned short*)smem_f;     // [8c][16b][RSC chunks][8]

    const int tid = threadIdx.x, l = tid & 63, wv = tid >> 6;   // wv = local channel
    const int m = l & 15, kg = l >> 4;
    const int btile = (blockIdx.x & 7) | ((blockIdx.x >> 6) << 3);   // 0..63
    const int cg    = (blockIdx.x >> 3) & 7;
    const int b0 = btile * 16, c0 = cg * 8;

    // ---- stage X: ALL loads first (one drain region), then convert+write.
    // 768 tasks (cq 2, b 16, kchunk 24) over 512 threads.
    floatx4 f[2][8];
    #pragma unroll
    for (int i = 0; i < 2; ++i) {
        int v = tid + i * 512;
        if (v < 768) {
            int cq = v & 1, b = (v >> 1) & 15, kchunk = v >> 5;   // 0..23
            #pragma unroll
            for (int j = 0; j < 8; ++j) {
                int o = kchunk * 8 + j;
                floatx4 z = {0.f, 0.f, 0.f, 0.f};
                f[i][j] = (o < ORD)
                    ? *(const floatx4*)(inp + ((size_t)(b0 + b) * SEQ + OFF + o) * CCH + c0 + cq * 4)
                    : z;
            }
        }
    }
    #pragma unroll
    for (int i = 0; i < 2; ++i) {
        int v = tid + i * 512;
        if (v < 768) {
            int cq = v & 1, b = (v >> 1) & 15, kchunk = v >> 5;
            #pragma unroll
            for (int cc = 0; cc < 4; ++cc) {
                int c = cq * 4 + cc;             // local channel 0..7
                ushort8 u;
                #pragma unroll
                for (int j = 0; j < 8; ++j) u[j] = f2bf(f[i][j][cc]);
                *(ushort8*)(Xs + (((c * 16 + b) * RSC + (kchunk ^ (c & 7))) << 3)) = u;
            }
        }
    }

    // bias for this wave's channel (lane's t = n*16+m)
    float bv[6];
    #pragma unroll
    for (int n = 0; n < 6; ++n)
        bv[n] = bias[(c0 + wv) * TT + n * 16 + m];

    __syncthreads();

    // ---- compute: wave wv handles channel wv: 16b x 96t x 192k
    floatx4 acc[6] = {};
    {
        const int c = wv;
        short8 a[6];
        #pragma unroll
        for (int kc = 0; kc < 6; ++kc) {
            int chunk = (kc * 4 + kg) ^ (c & 7);
            a[kc] = *(const short8*)(Xs + (((c * 16 + m) * RSC + chunk) << 3));
        }
        const unsigned short* Wc = Wt2 + (size_t)(c0 + c) * 36 * 512;
        #pragma unroll
        for (int kc = 0; kc < 6; ++kc) {
            #pragma unroll
            for (int n = 0; n < 6; ++n) {
                short8 bfrag = *(const short8*)(Wc + (size_t)(n * 6 + kc) * 512 + l * 8);
                acc[n] = __builtin_amdgcn_mfma_f32_16x16x32_bf16(a[kc], bfrag, acc[n], 0, 0, 0);
            }
        }
    }

    __syncthreads();   // done reading Xs; reuse as Ys

    // ---- single-shot epilogue: Ys[row][t][c] pad-9 -> 16-B c-runs to global
    float* Ys = smem_f;
    {
        const int c = wv;
        #pragma unroll
        for (int n = 0; n < 6; ++n)
            #pragma unroll
            for (int r = 0; r < 4; ++r) {
                int row = kg * 4 + r;            // D row = local b
                Ys[(row * TT + n * 16 + m) * YSTR + c] = acc[n][r] + bv[n];
            }
    }
    __syncthreads();
    {
        int c4  = tid & 1;
        int te  = (tid >> 1) & 15;
        int row = tid >> 5;                      // 0..15
        #pragma unroll
        for (int s = 0; s < 6; ++s) {
            int tt = te + s * 16;
            floatx4 y = *(const floatx4*)(Ys + (row * TT + tt) * YSTR + c4 * 4);
            *(floatx4*)(out + ((size_t)(b0 + row) * TT + tt) * CCH + c0 + c4 * 4) = y;
        }
    }
}

// ===== fallback (round-2 kernel) if ws too small =====
#define MB  8
#define NT  16
#define KO  8
#define NCH (ORD/KO)
#define WSTRIDE 132
typedef __attribute__((address_space(3))) void* lds_ptr_t;
typedef const __attribute__((address_space(1))) void* gbl_ptr_t;

__global__ __launch_bounds__(256, 4)
void tcl_fallback(const float* __restrict__ inp, const float* __restrict__ W,
                  const float* __restrict__ bias, float* __restrict__ out)
{
    __shared__ float Xsf[MB * KO * CCH];
    __shared__ float Wsf[CCH * WSTRIDE];
    const int tid = threadIdx.x;
    const int c   = tid & 63;
    const int tg  = tid >> 6;
    const int bblk = blockIdx.x & 127;
    const int tblk = blockIdx.x >> 7;
    const int b0 = bblk * MB;
    const int t0 = tblk * NT;
    float acc[MB][4];
    #pragma unroll
    for (int bi = 0; bi < MB; ++bi)
        #pragma unroll
        for (int tj = 0; tj < 4; ++tj) acc[bi][tj] = 0.f;
    for (int ch = 0; ch < NCH; ++ch) {
        const int ob = ch * KO;
        #pragma unroll
        for (int k = 0; k < 4; ++k) {
            int v = tid + k * 256;
            int row = v >> 4, c4 = v & 15;
            int bi = row >> 3, oi = row & 7;
            const float* gp = inp + ((size_t)(b0 + bi) * SEQ + (OFF + ob + oi)) * CCH + c4 * 4;
            __builtin_amdgcn_global_load_lds((gbl_ptr_t)gp, (lds_ptr_t)(Xsf + v * 4), 16, 0, 0);
        }
        float4 wbuf[8];
        #pragma unroll
        for (int k = 0; k < 8; ++k) {
            int v = tid + k * 256;
            int cch = v >> 5, oi = (v >> 2) & 7, t4 = v & 3;
            wbuf[k] = *(const float4*)(W + (size_t)cch * (ORD * TT) + (size_t)(ob + oi) * TT + t0 + t4 * 4);
        }
        #pragma unroll
        for (int k = 0; k < 8; ++k) {
            int v = tid + k * 256;
            int cch = v >> 5, oi = (v >> 2) & 7, t4 = v & 3;
            *(float4*)(Wsf + cch * WSTRIDE + oi * NT + t4 * 4) = wbuf[k];
        }
        __syncthreads();
        #pragma unroll
        for (int oi = 0; oi < KO; ++oi) {
            const float4 wvv = *(const float4*)(Wsf + c * WSTRIDE + oi * NT + tg * 4);
            float xv[MB];
            #pragma unroll
            for (int bi = 0; bi < MB; ++bi) xv[bi] = Xsf[(bi * KO + oi) * CCH + c];
            #pragma unroll
            for (int bi = 0; bi < MB; ++bi) {
                acc[bi][0] += xv[bi] * wvv.x;
                acc[bi][1] += xv[bi] * wvv.y;
                acc[bi][2] += xv[bi] * wvv.z;
                acc[bi][3] += xv[bi] * wvv.w;
            }
        }
        __syncthreads();
    }
    const float4 bvv = *(const float4*)(bias + c * TT + t0 + tg * 4);
    #pragma unroll
    for (int bi = 0; bi < MB; ++bi) {
        size_t base = ((size_t)(b0 + bi) * TT + (t0 + tg * 4)) * CCH + c;
        out[base]           = acc[bi][0] + bvv.x;
        out[base + CCH]     = acc[bi][1] + bvv.y;
        out[base + 2 * CCH] = acc[bi][2] + bvv.z;
        out[base + 3 * CCH] = acc[bi][3] + bvv.w;
    }
}

extern "C" void kernel_launch(void* const* d_in, const int* in_sizes, int n_in,
                              void* d_out, int out_size, void* d_ws, size_t ws_size,
                              hipStream_t stream) {
    const float* inp  = (const float*)d_in[0];   // [1024][336][64]
    const float* W    = (const float*)d_in[1];   // [64][168][96]
    const float* bias = (const float*)d_in[2];   // [64][96]
    float* out = (float*)d_out;                  // [1024][96][64]

    if (ws_size >= WS_NEED) {
        unsigned short* Wt2 = (unsigned short*)d_ws;
        k1w<<<576, 256, 0, stream>>>(W, Wt2);
        k2f<<<512, 512, 0, stream>>>(inp, Wt2, bias, out);
    } else {
        tcl_fallback<<<768, 256, 0, stream>>>(inp, W, bias, out);
    }
}